// Round 1
// baseline (1209.057 us; speedup 1.0000x reference)
//
#include <hip/hip_runtime.h>
#include <hip/hip_bf16.h>
#include <math.h>

#define NFEAT 512
#define NHID 256
#define NCLASS 10

typedef unsigned short u16;
using frag_ab = __attribute__((ext_vector_type(8))) short;   // 8 bf16
using frag_cd = __attribute__((ext_vector_type(4))) float;   // 4 f32

__device__ inline u16 f2bf(float f) {
    __hip_bfloat16 b = __float2bfloat16(f);
    return __builtin_bit_cast(unsigned short, b);
}
__device__ inline float bf2f(u16 u) {
    unsigned int t = ((unsigned int)u) << 16;
    return __builtin_bit_cast(float, t);
}

// ---------------- prep kernels ----------------

__global__ void k_zero(int* p, int n) {
    int i = blockIdx.x * 256 + threadIdx.x;
    if (i < n) p[i] = 0;
}

// W1 [512,256] f32 -> W1T [256,512] bf16
__global__ void k_w1t(const float* __restrict__ W1, u16* __restrict__ W1T) {
    int i = blockIdx.x * 256 + threadIdx.x;   // i < NFEAT*NHID
    int k = i / NHID, n = i % NHID;
    W1T[n * NFEAT + k] = f2bf(W1[i]);
}

__global__ void k_hist(const int* __restrict__ dst, int* __restrict__ deg, int E) {
    int e = blockIdx.x * 256 + threadIdx.x;
    if (e < E) atomicAdd(&deg[dst[e]], 1);
}

// inclusive scan within 256-blocks
__global__ void k_scan1(const int* __restrict__ deg, int* __restrict__ partial,
                        int* __restrict__ bsums, int n) {
    __shared__ int tmp[256];
    int tid = threadIdx.x;
    int i = blockIdx.x * 256 + tid;
    tmp[tid] = (i < n) ? deg[i] : 0;
    __syncthreads();
    for (int off = 1; off < 256; off <<= 1) {
        int t = (tid >= off) ? tmp[tid - off] : 0;
        __syncthreads();
        tmp[tid] += t;
        __syncthreads();
    }
    if (i < n) partial[i] = tmp[tid];
    if (tid == 255) bsums[blockIdx.x] = tmp[255];
}

// inclusive scan of block sums (nb <= 512)
__global__ void k_scan2(const int* __restrict__ bsums, int* __restrict__ bsums2, int nb) {
    __shared__ int tmp[512];
    int tid = threadIdx.x;
    tmp[tid] = (tid < nb) ? bsums[tid] : 0;
    __syncthreads();
    for (int off = 1; off < 512; off <<= 1) {
        int t = (tid >= off) ? tmp[tid - off] : 0;
        __syncthreads();
        tmp[tid] += t;
        __syncthreads();
    }
    if (tid < nb) bsums2[tid] = tmp[tid];
}

// rowptr[0]=0 ; rowptr[i+1] = inclusive_scan(deg)[i]
__global__ void k_scan3(const int* __restrict__ partial, const int* __restrict__ bsums2,
                        int* __restrict__ rowptr, int n) {
    int i = blockIdx.x * 256 + threadIdx.x;
    if (i < n) {
        int add = (blockIdx.x > 0) ? bsums2[blockIdx.x - 1] : 0;
        rowptr[i + 1] = partial[i] + add;
        if (i == 0) rowptr[0] = 0;
    }
}

__global__ void k_scatter(const int* __restrict__ src, const int* __restrict__ dst,
                          const float* __restrict__ w, const int* __restrict__ rowptr,
                          int* __restrict__ cursor, int* __restrict__ esrc,
                          float* __restrict__ ews, int E) {
    int e = blockIdx.x * 256 + threadIdx.x;
    if (e >= E) return;
    int d = dst[e];
    int p = rowptr[d] + atomicAdd(&cursor[d], 1);
    esrc[p] = src[e];
    ews[p] = w[e];
}

// ---------------- layer 1: support1 = x @ W1 (bf16 MFMA) ----------------
// block = 256 thr = 4 waves; wave computes rows [base,base+16) x all 256 cols
// (16 accumulators of 16x16). A: fp32 loads converted to bf16 in-flight.
__global__ void k_gemm1(const float* __restrict__ x, const u16* __restrict__ W1T,
                        u16* __restrict__ sup1, int N) {
    int wid = threadIdx.x >> 6;
    int lane = threadIdx.x & 63;
    int rowbase = blockIdx.x * 64 + wid * 16;
    int lrow = lane & 15;
    int kq = lane >> 4;                     // 0..3
    int row = rowbase + lrow;
    if (row >= N) row = N - 1;              // clamp (store is guarded)
    const float* xrow = x + (long)row * NFEAT;

    frag_cd acc[16];
#pragma unroll
    for (int t = 0; t < 16; t++) acc[t] = (frag_cd){0.f, 0.f, 0.f, 0.f};

    for (int k0 = 0; k0 < NFEAT; k0 += 32) {
        int ko = k0 + kq * 8;
        float4 a0 = *(const float4*)(xrow + ko);
        float4 a1 = *(const float4*)(xrow + ko + 4);
        frag_ab af;
        af[0] = (short)f2bf(a0.x); af[1] = (short)f2bf(a0.y);
        af[2] = (short)f2bf(a0.z); af[3] = (short)f2bf(a0.w);
        af[4] = (short)f2bf(a1.x); af[5] = (short)f2bf(a1.y);
        af[6] = (short)f2bf(a1.z); af[7] = (short)f2bf(a1.w);
#pragma unroll
        for (int nt = 0; nt < 16; nt++) {
            frag_ab bfr = *(const frag_ab*)(W1T + (long)(nt * 16 + lrow) * NFEAT + ko);
            acc[nt] = __builtin_amdgcn_mfma_f32_16x16x32_bf16(af, bfr, acc[nt], 0, 0, 0);
        }
    }
    // C/D layout: col = lane&15, row = (lane>>4)*4 + reg
#pragma unroll
    for (int nt = 0; nt < 16; nt++) {
#pragma unroll
        for (int r = 0; r < 4; r++) {
            int grow = rowbase + kq * 4 + r;
            if (grow < N)
                sup1[(long)grow * NHID + nt * 16 + lrow] = f2bf(acc[nt][r]);
        }
    }
}

// ---------------- agg1: h = relu(sum_e w*sup1[src] + b1), bf16 out ---------
// one block (256 thr) per dst node; tid = feature
__global__ void k_agg1(const u16* __restrict__ sup1, const int* __restrict__ rowptr,
                       const int* __restrict__ esrc, const float* __restrict__ ews,
                       const float* __restrict__ b1, u16* __restrict__ h, int N) {
    __shared__ int ls[256];
    __shared__ float lw[256];
    int node = blockIdx.x;
    int tid = threadIdx.x;
    int rp0 = rowptr[node], rp1 = rowptr[node + 1];
    float acc = 0.f;
    for (int base = rp0; base < rp1; base += 256) {
        int cnt = min(256, rp1 - base);
        __syncthreads();
        if (tid < cnt) { ls[tid] = esrc[base + tid]; lw[tid] = ews[base + tid]; }
        __syncthreads();
        for (int j = 0; j < cnt; j++)
            acc += lw[j] * bf2f(sup1[(long)ls[j] * NHID + tid]);
    }
    float v = acc + b1[tid];
    h[(long)node * NHID + tid] = f2bf(fmaxf(v, 0.f));
}

// ---------------- layer 2 dense: sup2 = h @ W2 (fp32, LDS-tiled) -----------
// block 256 thr handles 64 nodes
__global__ void k_gemm2(const u16* __restrict__ h, const float* __restrict__ W2,
                        float* __restrict__ sup2, int N) {
    __shared__ u16 lh[64 * 258];            // +2 pad -> odd dword stride
    __shared__ float lw2[NHID * NCLASS];
    int tid = threadIdx.x;
    int g0 = blockIdx.x * 64;
    for (int i = tid; i < NHID * NCLASS; i += 256) lw2[i] = W2[i];
    for (int g = tid; g < 64 * 64; g += 256) {   // ushort4 groups
        int nl = g >> 6, k4 = (g & 63) << 2;
        int gn = g0 + nl;
        ushort4 v;
        v.x = v.y = v.z = v.w = 0;
        if (gn < N) v = *(const ushort4*)(h + (long)gn * NHID + k4);
        int o = nl * 258 + k4;
        lh[o] = v.x; lh[o + 1] = v.y; lh[o + 2] = v.z; lh[o + 3] = v.w;
    }
    __syncthreads();
    for (int t = tid; t < 64 * NCLASS; t += 256) {
        int nl = t / NCLASS, c = t % NCLASS;
        int gn = g0 + nl;
        const u16* hr = lh + nl * 258;
        float s = 0.f;
#pragma unroll 4
        for (int k = 0; k < NHID; k++) s += bf2f(hr[k]) * lw2[k * NCLASS + c];
        if (gn < N) sup2[(long)gn * NCLASS + c] = s;
    }
}

// ---------------- agg2 + bias + log_softmax: one wave per node -------------
__global__ void k_out(const float* __restrict__ sup2, const int* __restrict__ rowptr,
                      const int* __restrict__ esrc, const float* __restrict__ ews,
                      const float* __restrict__ b2, float* __restrict__ out, int N) {
    int wid = threadIdx.x >> 6, lane = threadIdx.x & 63;
    int node = blockIdx.x * 4 + wid;
    if (node >= N) return;
    int rp0 = rowptr[node], rp1 = rowptr[node + 1];
    float acc[NCLASS];
#pragma unroll
    for (int c = 0; c < NCLASS; c++) acc[c] = 0.f;
    for (int e = rp0 + lane; e < rp1; e += 64) {
        int s = esrc[e];
        float w = ews[e];
        const float* sr = sup2 + (long)s * NCLASS;
#pragma unroll
        for (int c = 0; c < NCLASS; c++) acc[c] += w * sr[c];
    }
#pragma unroll
    for (int c = 0; c < NCLASS; c++) {
#pragma unroll
        for (int m = 1; m < 64; m <<= 1) acc[c] += __shfl_xor(acc[c], m, 64);
    }
    float logit[NCLASS], mx = -1e30f;
#pragma unroll
    for (int c = 0; c < NCLASS; c++) { logit[c] = acc[c] + b2[c]; mx = fmaxf(mx, logit[c]); }
    float se = 0.f;
#pragma unroll
    for (int c = 0; c < NCLASS; c++) se += expf(logit[c] - mx);
    float lse = mx + logf(se);
    if (lane < NCLASS) {
        float v = 0.f;
#pragma unroll
        for (int c = 0; c < NCLASS; c++) if (lane == c) v = logit[c] - lse;
        out[(long)node * NCLASS + lane] = v;
    }
}

// ---------------- launch ----------------

extern "C" void kernel_launch(void* const* d_in, const int* in_sizes, int n_in,
                              void* d_out, int out_size, void* d_ws, size_t ws_size,
                              hipStream_t stream) {
    const float* x   = (const float*)d_in[0];
    const int* esrc0 = (const int*)d_in[1];
    const int* edst0 = (const int*)d_in[2];
    const float* ew0 = (const float*)d_in[3];
    const float* W1  = (const float*)d_in[4];
    const float* b1  = (const float*)d_in[5];
    const float* W2  = (const float*)d_in[6];
    const float* b2  = (const float*)d_in[7];
    float* out = (float*)d_out;

    const int N = in_sizes[0] / NFEAT;     // 100000
    const int E = in_sizes[1];             // 3200000
    const int NB1 = (N + 255) / 256;       // 391

    char* ws = (char*)d_ws;
    size_t off = 0;
    auto alloc = [&](size_t bytes) -> void* {
        off = (off + 255) & ~(size_t)255;
        void* p = ws + off;
        off += bytes;
        return p;
    };
    u16*  sup1   = (u16*)alloc((size_t)N * NHID * 2);
    u16*  h      = (u16*)alloc((size_t)N * NHID * 2);
    float* sup2  = (float*)alloc((size_t)N * NCLASS * 4);
    u16*  W1T    = (u16*)alloc((size_t)NFEAT * NHID * 2);
    int*  deg    = (int*)alloc((size_t)N * 4);
    int*  cursor = (int*)alloc((size_t)N * 4);
    int*  rowptr = (int*)alloc((size_t)(N + 1) * 4);
    int*  partial= (int*)alloc((size_t)N * 4);
    int*  bsums  = (int*)alloc((size_t)NB1 * 4);
    int*  bsums2 = (int*)alloc((size_t)NB1 * 4);
    int*  esrc   = (int*)alloc((size_t)E * 4);
    float* ews   = (float*)alloc((size_t)E * 4);

    // CSR build
    k_zero<<<NB1, 256, 0, stream>>>(deg, N);
    k_zero<<<NB1, 256, 0, stream>>>(cursor, N);
    k_hist<<<(E + 255) / 256, 256, 0, stream>>>(edst0, deg, E);
    k_scan1<<<NB1, 256, 0, stream>>>(deg, partial, bsums, N);
    k_scan2<<<1, 512, 0, stream>>>(bsums, bsums2, NB1);
    k_scan3<<<NB1, 256, 0, stream>>>(partial, bsums2, rowptr, N);
    k_scatter<<<(E + 255) / 256, 256, 0, stream>>>(esrc0, edst0, ew0, rowptr, cursor,
                                                   esrc, ews, E);
    // layer 1
    k_w1t<<<(NFEAT * NHID) / 256, 256, 0, stream>>>(W1, W1T);
    k_gemm1<<<(N + 63) / 64, 256, 0, stream>>>(x, W1T, sup1, N);
    k_agg1<<<N, 256, 0, stream>>>(sup1, rowptr, esrc, ews, b1, h, N);
    // layer 2
    k_gemm2<<<(N + 63) / 64, 256, 0, stream>>>(h, W2, sup2, N);
    k_out<<<(N + 3) / 4, 256, 0, stream>>>(sup2, rowptr, esrc, ews, b2, out, N);
}

// Round 2
// 1052.271 us; speedup vs baseline: 1.1490x; 1.1490x over previous
//
#include <hip/hip_runtime.h>
#include <hip/hip_bf16.h>
#include <math.h>

#define NFEAT 512
#define NHID 256
#define NCLASS 10

typedef unsigned short u16;
using frag_ab = __attribute__((ext_vector_type(8))) short;   // 8 bf16
using frag_cd = __attribute__((ext_vector_type(4))) float;   // 4 f32

__device__ inline u16 f2bf(float f) {
    __hip_bfloat16 b = __float2bfloat16(f);
    return __builtin_bit_cast(unsigned short, b);
}
__device__ inline float bf2f(u16 u) {
    unsigned int t = ((unsigned int)u) << 16;
    return __builtin_bit_cast(float, t);
}

// ---------------- prep kernels ----------------

__global__ void k_zero(int* p, int n) {
    int i = blockIdx.x * 256 + threadIdx.x;
    if (i < n) p[i] = 0;
}

// W1 [512,256] f32 -> W1T [256,512] bf16
__global__ void k_w1t(const float* __restrict__ W1, u16* __restrict__ W1T) {
    int i = blockIdx.x * 256 + threadIdx.x;   // i < NFEAT*NHID
    int k = i / NHID, n = i % NHID;
    W1T[n * NFEAT + k] = f2bf(W1[i]);
}

__global__ void k_hist(const int* __restrict__ dst, int* __restrict__ deg, int E) {
    int e = blockIdx.x * 256 + threadIdx.x;
    if (e < E) atomicAdd(&deg[dst[e]], 1);
}

// inclusive scan within 256-blocks
__global__ void k_scan1(const int* __restrict__ deg, int* __restrict__ partial,
                        int* __restrict__ bsums, int n) {
    __shared__ int tmp[256];
    int tid = threadIdx.x;
    int i = blockIdx.x * 256 + tid;
    tmp[tid] = (i < n) ? deg[i] : 0;
    __syncthreads();
    for (int off = 1; off < 256; off <<= 1) {
        int t = (tid >= off) ? tmp[tid - off] : 0;
        __syncthreads();
        tmp[tid] += t;
        __syncthreads();
    }
    if (i < n) partial[i] = tmp[tid];
    if (tid == 255) bsums[blockIdx.x] = tmp[255];
}

// inclusive scan of block sums (nb <= 512)
__global__ void k_scan2(const int* __restrict__ bsums, int* __restrict__ bsums2, int nb) {
    __shared__ int tmp[512];
    int tid = threadIdx.x;
    tmp[tid] = (tid < nb) ? bsums[tid] : 0;
    __syncthreads();
    for (int off = 1; off < 512; off <<= 1) {
        int t = (tid >= off) ? tmp[tid - off] : 0;
        __syncthreads();
        tmp[tid] += t;
        __syncthreads();
    }
    if (tid < nb) bsums2[tid] = tmp[tid];
}

// rowptr[0]=0 ; rowptr[i+1] = inclusive_scan(deg)[i]
__global__ void k_scan3(const int* __restrict__ partial, const int* __restrict__ bsums2,
                        int* __restrict__ rowptr, int n) {
    int i = blockIdx.x * 256 + threadIdx.x;
    if (i < n) {
        int add = (blockIdx.x > 0) ? bsums2[blockIdx.x - 1] : 0;
        rowptr[i + 1] = partial[i] + add;
        if (i == 0) rowptr[0] = 0;
    }
}

__global__ void k_scatter(const int* __restrict__ src, const int* __restrict__ dst,
                          const float* __restrict__ w, const int* __restrict__ rowptr,
                          int* __restrict__ cursor, int* __restrict__ esrc,
                          float* __restrict__ ews, int E) {
    int e = blockIdx.x * 256 + threadIdx.x;
    if (e >= E) return;
    int d = dst[e];
    int p = rowptr[d] + atomicAdd(&cursor[d], 1);
    esrc[p] = src[e];
    ews[p] = w[e];
}

// ---------------- layer 1: support1 = x @ W1 (bf16 MFMA, LDS-staged B) -----
// block = 256 thr = 4 waves; tile M=128 x N=256. Wave owns 32 rows (2 x 16-row
// subtiles) so each B-fragment ds_read feeds 2 MFMAs. B chunk (256n x 32k)
// staged in LDS, row stride 80 B (16B-aligned, 20-bank shift -> 2-way = free).
#define BROW_STRIDE_B 80
__global__ __launch_bounds__(256, 2)
void k_gemm1(const float* __restrict__ x, const u16* __restrict__ W1T,
             u16* __restrict__ sup1, int N) {
    __shared__ char lB[256 * BROW_STRIDE_B];   // 20 KB
    int tid = threadIdx.x;
    int wid = tid >> 6, lane = tid & 63;
    int lrow = lane & 15, kq = lane >> 4;      // kq: 0..3
    long rowbase = (long)blockIdx.x * 128;

    long r0 = rowbase + wid * 32 + lrow;
    long r1 = r0 + 16;
    long ra0 = (r0 < N) ? r0 : (long)(N - 1);
    long ra1 = (r1 < N) ? r1 : (long)(N - 1);
    const float* xr0 = x + ra0 * NFEAT;
    const float* xr1 = x + ra1 * NFEAT;

    frag_cd acc[2][16];
#pragma unroll
    for (int t = 0; t < 2; t++)
#pragma unroll
        for (int nt = 0; nt < 16; nt++) acc[t][nt] = (frag_cd){0.f, 0.f, 0.f, 0.f};

    for (int k0 = 0; k0 < NFEAT; k0 += 32) {
        __syncthreads();                       // previous chunk fully consumed
#pragma unroll
        for (int j = 0; j < 4; j++) {          // stage 256 rows x 64 B
            int id = j * 256 + tid;            // 0..1023
            int n = id >> 2, q = id & 3;
            int4 v = *(const int4*)(W1T + n * NFEAT + k0 + q * 8);
            *(int4*)(lB + n * BROW_STRIDE_B + q * 16) = v;
        }
        __syncthreads();

        int ko = k0 + kq * 8;
        float4 a00 = *(const float4*)(xr0 + ko);
        float4 a01 = *(const float4*)(xr0 + ko + 4);
        float4 a10 = *(const float4*)(xr1 + ko);
        float4 a11 = *(const float4*)(xr1 + ko + 4);
        frag_ab af0, af1;
        af0[0] = (short)f2bf(a00.x); af0[1] = (short)f2bf(a00.y);
        af0[2] = (short)f2bf(a00.z); af0[3] = (short)f2bf(a00.w);
        af0[4] = (short)f2bf(a01.x); af0[5] = (short)f2bf(a01.y);
        af0[6] = (short)f2bf(a01.z); af0[7] = (short)f2bf(a01.w);
        af1[0] = (short)f2bf(a10.x); af1[1] = (short)f2bf(a10.y);
        af1[2] = (short)f2bf(a10.z); af1[3] = (short)f2bf(a10.w);
        af1[4] = (short)f2bf(a11.x); af1[5] = (short)f2bf(a11.y);
        af1[6] = (short)f2bf(a11.z); af1[7] = (short)f2bf(a11.w);

        const char* lbase = lB + lrow * BROW_STRIDE_B + kq * 16;
#pragma unroll
        for (int nt = 0; nt < 16; nt++) {
            frag_ab bfr = *(const frag_ab*)(lbase + nt * 16 * BROW_STRIDE_B);
            acc[0][nt] = __builtin_amdgcn_mfma_f32_16x16x32_bf16(af0, bfr, acc[0][nt], 0, 0, 0);
            acc[1][nt] = __builtin_amdgcn_mfma_f32_16x16x32_bf16(af1, bfr, acc[1][nt], 0, 0, 0);
        }
    }

    // C/D layout: col = lane&15, row = (lane>>4)*4 + reg
#pragma unroll
    for (int t = 0; t < 2; t++) {
#pragma unroll
        for (int nt = 0; nt < 16; nt++) {
#pragma unroll
            for (int r = 0; r < 4; r++) {
                long grow = rowbase + wid * 32 + t * 16 + kq * 4 + r;
                if (grow < N)
                    sup1[grow * NHID + nt * 16 + lrow] = f2bf(acc[t][nt][r]);
            }
        }
    }
}

// ---------------- agg1: h = relu(sum_e w*sup1[src] + b1), bf16 out ---------
// one wave per node; lane owns 4 consecutive features (8B gather per edge)
__global__ void k_agg1(const u16* __restrict__ sup1, const int* __restrict__ rowptr,
                       const int* __restrict__ esrc, const float* __restrict__ ews,
                       const float* __restrict__ b1, u16* __restrict__ h, int N) {
    int wid = threadIdx.x >> 6, lane = threadIdx.x & 63;
    int node = blockIdx.x * 4 + wid;
    if (node >= N) return;
    int rp0 = rowptr[node], rp1 = rowptr[node + 1];
    float a0 = 0.f, a1 = 0.f, a2 = 0.f, a3 = 0.f;
    int e = rp0;
    for (; e + 2 <= rp1; e += 2) {
        int s0 = esrc[e], s1 = esrc[e + 1];
        float w0 = ews[e], w1 = ews[e + 1];
        ushort4 v0 = *(const ushort4*)(sup1 + (long)s0 * NHID + lane * 4);
        ushort4 v1 = *(const ushort4*)(sup1 + (long)s1 * NHID + lane * 4);
        a0 += w0 * bf2f(v0.x); a1 += w0 * bf2f(v0.y);
        a2 += w0 * bf2f(v0.z); a3 += w0 * bf2f(v0.w);
        a0 += w1 * bf2f(v1.x); a1 += w1 * bf2f(v1.y);
        a2 += w1 * bf2f(v1.z); a3 += w1 * bf2f(v1.w);
    }
    if (e < rp1) {
        int s0 = esrc[e];
        float w0 = ews[e];
        ushort4 v0 = *(const ushort4*)(sup1 + (long)s0 * NHID + lane * 4);
        a0 += w0 * bf2f(v0.x); a1 += w0 * bf2f(v0.y);
        a2 += w0 * bf2f(v0.z); a3 += w0 * bf2f(v0.w);
    }
    float4 bb = *(const float4*)(b1 + lane * 4);
    ushort4 o;
    o.x = f2bf(fmaxf(a0 + bb.x, 0.f));
    o.y = f2bf(fmaxf(a1 + bb.y, 0.f));
    o.z = f2bf(fmaxf(a2 + bb.z, 0.f));
    o.w = f2bf(fmaxf(a3 + bb.w, 0.f));
    *(ushort4*)(h + (long)node * NHID + lane * 4) = o;
}

// ---------------- layer 2 dense: sup2 = h @ W2 (fp32, LDS-tiled) -----------
// block 256 thr handles 64 nodes
__global__ void k_gemm2(const u16* __restrict__ h, const float* __restrict__ W2,
                        float* __restrict__ sup2, int N) {
    __shared__ u16 lh[64 * 258];            // +2 pad -> odd dword stride
    __shared__ float lw2[NHID * NCLASS];
    int tid = threadIdx.x;
    int g0 = blockIdx.x * 64;
    for (int i = tid; i < NHID * NCLASS; i += 256) lw2[i] = W2[i];
    for (int g = tid; g < 64 * 64; g += 256) {   // ushort4 groups
        int nl = g >> 6, k4 = (g & 63) << 2;
        int gn = g0 + nl;
        ushort4 v;
        v.x = v.y = v.z = v.w = 0;
        if (gn < N) v = *(const ushort4*)(h + (long)gn * NHID + k4);
        int o = nl * 258 + k4;
        lh[o] = v.x; lh[o + 1] = v.y; lh[o + 2] = v.z; lh[o + 3] = v.w;
    }
    __syncthreads();
    for (int t = tid; t < 64 * NCLASS; t += 256) {
        int nl = t / NCLASS, c = t % NCLASS;
        int gn = g0 + nl;
        const u16* hr = lh + nl * 258;
        float s = 0.f;
#pragma unroll 4
        for (int k = 0; k < NHID; k++) s += bf2f(hr[k]) * lw2[k * NCLASS + c];
        if (gn < N) sup2[(long)gn * NCLASS + c] = s;
    }
}

// ---------------- agg2 + bias + log_softmax: one wave per node -------------
__global__ void k_out(const float* __restrict__ sup2, const int* __restrict__ rowptr,
                      const int* __restrict__ esrc, const float* __restrict__ ews,
                      const float* __restrict__ b2, float* __restrict__ out, int N) {
    int wid = threadIdx.x >> 6, lane = threadIdx.x & 63;
    int node = blockIdx.x * 4 + wid;
    if (node >= N) return;
    int rp0 = rowptr[node], rp1 = rowptr[node + 1];
    float acc[NCLASS];
#pragma unroll
    for (int c = 0; c < NCLASS; c++) acc[c] = 0.f;
    for (int e = rp0 + lane; e < rp1; e += 64) {
        int s = esrc[e];
        float w = ews[e];
        const float* sr = sup2 + (long)s * NCLASS;
#pragma unroll
        for (int c = 0; c < NCLASS; c++) acc[c] += w * sr[c];
    }
#pragma unroll
    for (int c = 0; c < NCLASS; c++) {
#pragma unroll
        for (int m = 1; m < 64; m <<= 1) acc[c] += __shfl_xor(acc[c], m, 64);
    }
    float logit[NCLASS], mx = -1e30f;
#pragma unroll
    for (int c = 0; c < NCLASS; c++) { logit[c] = acc[c] + b2[c]; mx = fmaxf(mx, logit[c]); }
    float se = 0.f;
#pragma unroll
    for (int c = 0; c < NCLASS; c++) se += expf(logit[c] - mx);
    float lse = mx + logf(se);
    if (lane < NCLASS) {
        float v = 0.f;
#pragma unroll
        for (int c = 0; c < NCLASS; c++) if (lane == c) v = logit[c] - lse;
        out[(long)node * NCLASS + lane] = v;
    }
}

// ---------------- launch ----------------

extern "C" void kernel_launch(void* const* d_in, const int* in_sizes, int n_in,
                              void* d_out, int out_size, void* d_ws, size_t ws_size,
                              hipStream_t stream) {
    const float* x   = (const float*)d_in[0];
    const int* esrc0 = (const int*)d_in[1];
    const int* edst0 = (const int*)d_in[2];
    const float* ew0 = (const float*)d_in[3];
    const float* W1  = (const float*)d_in[4];
    const float* b1  = (const float*)d_in[5];
    const float* W2  = (const float*)d_in[6];
    const float* b2  = (const float*)d_in[7];
    float* out = (float*)d_out;

    const int N = in_sizes[0] / NFEAT;     // 100000
    const int E = in_sizes[1];             // 3200000
    const int NB1 = (N + 255) / 256;       // 391

    char* ws = (char*)d_ws;
    size_t off = 0;
    auto alloc = [&](size_t bytes) -> void* {
        off = (off + 255) & ~(size_t)255;
        void* p = ws + off;
        off += bytes;
        return p;
    };
    u16*  sup1   = (u16*)alloc((size_t)N * NHID * 2);
    u16*  h      = (u16*)alloc((size_t)N * NHID * 2);
    float* sup2  = (float*)alloc((size_t)N * NCLASS * 4);
    u16*  W1T    = (u16*)alloc((size_t)NFEAT * NHID * 2);
    int*  deg    = (int*)alloc((size_t)N * 4);
    int*  cursor = (int*)alloc((size_t)N * 4);
    int*  rowptr = (int*)alloc((size_t)(N + 1) * 4);
    int*  partial= (int*)alloc((size_t)N * 4);
    int*  bsums  = (int*)alloc((size_t)NB1 * 4);
    int*  bsums2 = (int*)alloc((size_t)NB1 * 4);
    int*  esrc   = (int*)alloc((size_t)E * 4);
    float* ews   = (float*)alloc((size_t)E * 4);

    // CSR build
    k_zero<<<NB1, 256, 0, stream>>>(deg, N);
    k_zero<<<NB1, 256, 0, stream>>>(cursor, N);
    k_hist<<<(E + 255) / 256, 256, 0, stream>>>(edst0, deg, E);
    k_scan1<<<NB1, 256, 0, stream>>>(deg, partial, bsums, N);
    k_scan2<<<1, 512, 0, stream>>>(bsums, bsums2, NB1);
    k_scan3<<<NB1, 256, 0, stream>>>(partial, bsums2, rowptr, N);
    k_scatter<<<(E + 255) / 256, 256, 0, stream>>>(esrc0, edst0, ew0, rowptr, cursor,
                                                   esrc, ews, E);
    // layer 1
    k_w1t<<<(NFEAT * NHID) / 256, 256, 0, stream>>>(W1, W1T);
    k_gemm1<<<(N + 127) / 128, 256, 0, stream>>>(x, W1T, sup1, N);
    k_agg1<<<(N + 3) / 4, 256, 0, stream>>>(sup1, rowptr, esrc, ews, b1, h, N);
    // layer 2
    k_gemm2<<<(N + 63) / 64, 256, 0, stream>>>(h, W2, sup2, N);
    k_out<<<(N + 3) / 4, 256, 0, stream>>>(sup2, rowptr, esrc, ews, b2, out, N);
}